// Round 3
// baseline (289.080 us; speedup 1.0000x reference)
//
#include <hip/hip_runtime.h>
#include <hip/hip_bf16.h>

typedef short s8v  __attribute__((ext_vector_type(8)));
typedef float f32x4 __attribute__((ext_vector_type(4)));

// RNE float -> bf16 bits
__device__ __forceinline__ unsigned short f2bf(float f) {
  unsigned int b = __float_as_uint(f);
  b += 0x7fffu + ((b >> 16) & 1u);
  return (unsigned short)(b >> 16);
}

// ---------------- prep_w: Wa/Wb and Wproj into MFMA-fragment order ----------------
// wab  : [nt<4][kt<8][lane<64][j<8]  = bf16 W[(p=nt*16+(lane&15))][c=kt*32+8*(lane>>4)+j], p<32->Wa else Wb
// wfrag: [nt<8][kt<32][lane<64][j<8] = bf16 Wproj[z=nt*16+(lane&15)][korig], k'=kt*32+8*(lane>>4)+j,
//        c=k'&31, d=k'>>5, korig=c*32+d   (k' = d*32+c permutation; kt == d)
__global__ __launch_bounds__(256) void prep_w_kernel(
    const float* __restrict__ Wa, const float* __restrict__ Wb,
    const float* __restrict__ Wproj,
    unsigned short* __restrict__ wab, unsigned short* __restrict__ wfrag) {
  int gid = blockIdx.x * 256 + threadIdx.x;
  if (gid < 16384) {
    int e = gid;
    int j = e & 7, lane = (e >> 3) & 63, kt = (e >> 9) & 7, nt = e >> 12;
    int p = nt * 16 + (lane & 15);
    int c = kt * 32 + ((lane >> 4) << 3) + j;
    float v = (p < 32) ? Wa[p * 256 + c] : Wb[(p - 32) * 256 + c];
    wab[e] = f2bf(v);
  } else {
    int e = gid - 16384;
    int j = e & 7, lane = (e >> 3) & 63, kt = (e >> 9) & 31, nt = e >> 14;
    int z = nt * 16 + (lane & 15);
    int kp = kt * 32 + ((lane >> 4) << 3) + j;
    int c = kp & 31, d = kp >> 5;
    wfrag[e] = f2bf(Wproj[z * 1024 + c * 32 + d]);
  }
}

// ---------------- kernel_a: LN + MFMA projection + fragment-order transpose ----------------
// block = (i, s-half): 768 blocks, 256 threads (4 waves).
// outputs afrag/bfrag: [rowblock rb<768][kt<4][lane<64][j<8] bf16,
//   element = a_t[rb*16+(lane&15)][s = kt*32 + 8*(lane>>4) + j],  a_t[(i*32+c)][s] = a[s,i,c]
//   afrag rb = i*2 + (c>>4);  bfrag rb = j*2 + (d>>4)
#define XS 264   // x_lds row stride (halfwords)
#define OS 66    // o_lds row stride (floats)
__global__ __launch_bounds__(256) void kernel_a(
    const float* __restrict__ msa, const float* __restrict__ gamma, const float* __restrict__ beta,
    const unsigned short* __restrict__ wab,
    unsigned short* __restrict__ afrag, unsigned short* __restrict__ bfrag) {
  __shared__ unsigned short xs[64 * XS];   // normalized x, bf16 [64 local s][256 c]
  __shared__ float os[64 * OS];            // proj result fp32 [64 local s][64 p]
  const int i  = blockIdx.x >> 1;
  const int sh = blockIdx.x & 1;           // s-half: s in [sh*64, sh*64+64)
  const int tid = threadIdx.x;
  const int w = tid >> 6, lane = tid & 63;
  const int gq = lane >> 4, nlo = lane & 15;

  const float4 g4  = *(const float4*)(gamma + lane * 4);
  const float4 be4 = *(const float4*)(beta  + lane * 4);

  // phase 1: LayerNorm, one row per wave per iter
  for (int it = 0; it < 16; ++it) {
    const int sl = it * 4 + w;
    const int s  = sh * 64 + sl;
    const float4 v = *(const float4*)(msa + (size_t)(s * 384 + i) * 256 + lane * 4);
    float sum = v.x + v.y + v.z + v.w;
    float sq  = fmaf(v.x, v.x, fmaf(v.y, v.y, fmaf(v.z, v.z, v.w * v.w)));
#pragma unroll
    for (int off = 32; off >= 1; off >>= 1) {
      sum += __shfl_xor(sum, off);
      sq  += __shfl_xor(sq,  off);
    }
    const float mu   = sum * (1.f / 256.f);
    const float var  = sq * (1.f / 256.f) - mu * mu;
    const float rstd = rsqrtf(var + 1e-5f);
    unsigned int lo = (unsigned int)f2bf((v.x - mu) * rstd * g4.x + be4.x)
                    | ((unsigned int)f2bf((v.y - mu) * rstd * g4.y + be4.y) << 16);
    unsigned int hi = (unsigned int)f2bf((v.z - mu) * rstd * g4.z + be4.z)
                    | ((unsigned int)f2bf((v.w - mu) * rstd * g4.w + be4.w) << 16);
    *(uint2*)&xs[sl * XS + lane * 4] = make_uint2(lo, hi);
  }
  __syncthreads();

  // phase 2: MFMA projection  o[s][p] = sum_c x[s][c] * W[p][c]; wave w owns rows w*16..+16
  const f32x4 z4 = {0.f, 0.f, 0.f, 0.f};
  f32x4 acc[4];
#pragma unroll
  for (int nt = 0; nt < 4; ++nt) acc[nt] = z4;
  for (int kt = 0; kt < 8; ++kt) {
    const s8v av = *(const s8v*)&xs[(w * 16 + nlo) * XS + kt * 32 + gq * 8];
#pragma unroll
    for (int nt = 0; nt < 4; ++nt) {
      const s8v bv = ((const s8v*)wab)[(nt * 8 + kt) * 64 + lane];
      acc[nt] = __builtin_amdgcn_mfma_f32_16x16x32_bf16(av, bv, acc[nt], 0, 0, 0);
    }
  }
#pragma unroll
  for (int nt = 0; nt < 4; ++nt)
#pragma unroll
    for (int r = 0; r < 4; ++r)
      os[(w * 16 + gq * 4 + r) * OS + nt * 16 + nlo] = acc[nt][r];
  __syncthreads();

  // phase 3: fragment-order transposed write to afrag/bfrag
#pragma unroll
  for (int q = 0; q < 2; ++q) {
    const int set = q * 256 + tid;           // < 512
    const int lf  = set & 63;                // fragment lane
    const int ktl = (set >> 6) & 1;          // local k-tile (32 s each)
    const int hi2 = (set >> 7) & 1;          // c/d half (16)
    const int mat = (set >> 8) & 1;          // 0 = a, 1 = b
    const int g2  = lf >> 4;
    const int p   = mat * 32 + (lf & 15) + 16 * hi2;
    s8v pk;
#pragma unroll
    for (int j = 0; j < 8; ++j) {
      const int srow = ktl * 32 + g2 * 8 + j;
      pk[j] = (short)f2bf(os[srow * OS + p]);
    }
    unsigned short* dst = mat ? bfrag : afrag;
    const int rb = i * 2 + hi2;
    const int kt = sh * 2 + ktl;
    *(s8v*)(dst + ((size_t)((rb * 4 + kt) * 64 + lf)) * 8) = pk;
  }
}

// ---------------- kernel_main: fused outer-product + projection, d-half chunked ----------------
// block = 8i x 8j tile (64 ij); 8 waves; 66.5KB LDS -> 2 blocks/CU; regs <= 128 -> 4 waves/SIMD.
// loop dc in {0,1} (d-half):
//   stage1: outer[m=(i,c)<256][n=(jl,dl)=jl*16+dl <128] = sum_s a_t[m][s] b_t[j*32+d][s], K=128
//           wave grid 4m x 2n, wave tile 64x64, acc[4][4]; bfrag rb = j*2+dc
//   t[row=iloc*8+jl <64][k''=dl*32+c <512] bf16 *1/128, stride TS3, XOR swizzle sig(dl)=((dl>>1)&7)<<3
//   stage2: acc2 += t * Wproj-chunk: M=64 ij, N=128 z, K=512 (kt2<16, global kt=dc*16+kt2)
//           wave grid 2ij x 4z, wave tile 32ij x 32z; each LDS read & each wv feed 2 MFMAs
#define TS3 520  // halfword row stride (1040B: +4 banks/row)
__global__ __launch_bounds__(512, 4) void kernel_main(
    const unsigned short* __restrict__ afrag, const unsigned short* __restrict__ bfrag,
    const unsigned short* __restrict__ wfrag, const float* __restrict__ bproj,
    float* __restrict__ out) {
  extern __shared__ unsigned short t[];      // [64][TS3]
  // bijective XCD swizzle: 2304 % 8 == 0 -> contiguous chunk of 288 per XCD
  const int bid = (blockIdx.x & 7) * 288 + (blockIdx.x >> 3);
  const int bi = bid / 48, bj = bid % 48;
  const int tid = threadIdx.x;
  const int wave = tid >> 6, lane = tid & 63;
  const int wm = wave >> 1, wn = wave & 1;   // stage1: 4m x 2n
  const int wmz = wave >> 2, wnz = wave & 3; // stage2: 2ij x 4z
  const int gq = lane >> 4, nlo = lane & 15;

  const f32x4 z4 = {0.f, 0.f, 0.f, 0.f};
  f32x4 acc2[2][2];
#pragma unroll
  for (int mt = 0; mt < 2; ++mt)
#pragma unroll
    for (int zt = 0; zt < 2; ++zt) acc2[mt][zt] = z4;

  const s8v* ag = (const s8v*)afrag;
  const s8v* bg = (const s8v*)bfrag;
  const s8v* wg = (const s8v*)wfrag;

  for (int dc = 0; dc < 2; ++dc) {
    // ---- stage 1: partial outer product for d-half dc ----
    f32x4 acc[4][4];
#pragma unroll
    for (int mt = 0; mt < 4; ++mt)
#pragma unroll
      for (int nt = 0; nt < 4; ++nt) acc[mt][nt] = z4;
#pragma unroll
    for (int kt = 0; kt < 4; ++kt) {
      s8v av[4];
#pragma unroll
      for (int mt = 0; mt < 4; ++mt)
        av[mt] = ag[((bi * 16 + wm * 4 + mt) * 4 + kt) * 64 + lane];
#pragma unroll
      for (int nt = 0; nt < 4; ++nt) {
        const s8v bv = bg[(((bj * 8 + wn * 4 + nt) * 2 + dc) * 4 + kt) * 64 + lane];
#pragma unroll
        for (int mt = 0; mt < 4; ++mt)
          acc[mt][nt] = __builtin_amdgcn_mfma_f32_16x16x32_bf16(av[mt], bv, acc[mt][nt], 0, 0, 0);
      }
    }

    if (dc) __syncthreads();   // all stage-2 reads of previous chunk done before overwrite

    // ---- write t: row = iloc*8 + jl, k'' = dl*32 + c, dl = nlo ----
#pragma unroll
    for (int mt = 0; mt < 4; ++mt) {
      const int rbase = (wm * 2 + (mt >> 1)) * 8;           // iloc*8
      const int c0 = (mt & 1) * 16 + gq * 4;
      const int hw = (nlo * 32 + c0) ^ (((nlo >> 1) & 7) << 3);
#pragma unroll
      for (int nt = 0; nt < 4; ++nt) {
        const int row = rbase + wn * 4 + nt;                // + jl
        const unsigned int lo = (unsigned int)f2bf(acc[mt][nt][0] * 0.0078125f)
                              | ((unsigned int)f2bf(acc[mt][nt][1] * 0.0078125f) << 16);
        const unsigned int hi = (unsigned int)f2bf(acc[mt][nt][2] * 0.0078125f)
                              | ((unsigned int)f2bf(acc[mt][nt][3] * 0.0078125f) << 16);
        *(uint2*)&t[row * TS3 + hw] = make_uint2(lo, hi);
      }
    }
    __syncthreads();

    // ---- stage 2: accumulate K=512 chunk ----
    for (int kt2 = 0; kt2 < 16; ++kt2) {
      const int hwb = (kt2 * 32 + gq * 8) ^ (((kt2 >> 1) & 7) << 3);
      s8v av2[2], wv[2];
#pragma unroll
      for (int mt = 0; mt < 2; ++mt)
        av2[mt] = *(const s8v*)&t[(wmz * 32 + mt * 16 + nlo) * TS3 + hwb];
#pragma unroll
      for (int zt = 0; zt < 2; ++zt)
        wv[zt] = wg[((wnz * 2 + zt) * 32 + dc * 16 + kt2) * 64 + lane];
#pragma unroll
      for (int mt = 0; mt < 2; ++mt)
#pragma unroll
        for (int zt = 0; zt < 2; ++zt)
          acc2[mt][zt] = __builtin_amdgcn_mfma_f32_16x16x32_bf16(av2[mt], wv[zt], acc2[mt][zt], 0, 0, 0);
    }
    if (!dc) __syncthreads();  // keep waves phase-aligned before t overwrite check at dc=1
  }

  // ---- epilogue ----
#pragma unroll
  for (int zt = 0; zt < 2; ++zt) {
    const int z = (wnz * 2 + zt) * 16 + nlo;
    const float bz = bproj[z];
#pragma unroll
    for (int mt = 0; mt < 2; ++mt)
#pragma unroll
      for (int r = 0; r < 4; ++r) {
        const int ij = wmz * 32 + mt * 16 + gq * 4 + r;
        const int gi = bi * 8 + (ij >> 3), gj = bj * 8 + (ij & 7);
        out[(size_t)(gi * 384 + gj) * 128 + z] = acc2[mt][zt][r] + bz;
      }
  }
}

extern "C" void kernel_launch(void* const* d_in, const int* in_sizes, int n_in,
                              void* d_out, int out_size, void* d_ws, size_t ws_size,
                              hipStream_t stream) {
  const float* msa   = (const float*)d_in[0];
  const float* gam   = (const float*)d_in[1];
  const float* bet   = (const float*)d_in[2];
  const float* Wa    = (const float*)d_in[3];
  const float* Wb    = (const float*)d_in[4];
  const float* Wproj = (const float*)d_in[5];
  const float* bpr   = (const float*)d_in[6];
  float* out = (float*)d_out;

  // workspace layout (bf16 elems): afrag 3MB, bfrag 3MB, wab 32KB, wfrag 256KB
  if (ws_size < 6586368) return;
  unsigned short* afrag = (unsigned short*)d_ws;
  unsigned short* bfrag = afrag + 1572864;
  unsigned short* wab   = bfrag + 1572864;
  unsigned short* wfr   = wab + 16384;

  (void)hipFuncSetAttribute(reinterpret_cast<const void*>(kernel_main),
                            hipFuncAttributeMaxDynamicSharedMemorySize, 64 * TS3 * 2);

  prep_w_kernel<<<576, 256, 0, stream>>>(Wa, Wb, Wproj, wab, wfr);
  kernel_a<<<768, 256, 0, stream>>>(msa, gam, bet, wab, afrag, bfrag);
  kernel_main<<<2304, 512, 64 * TS3 * 2, stream>>>(afrag, bfrag, wfr, bpr, out);
}

// Round 4
// 213.309 us; speedup vs baseline: 1.3552x; 1.3552x over previous
//
#include <hip/hip_runtime.h>
#include <hip/hip_bf16.h>

typedef short s8v  __attribute__((ext_vector_type(8)));
typedef float f32x4 __attribute__((ext_vector_type(4)));

// RNE float -> bf16 bits
__device__ __forceinline__ unsigned short f2bf(float f) {
  unsigned int b = __float_as_uint(f);
  b += 0x7fffu + ((b >> 16) & 1u);
  return (unsigned short)(b >> 16);
}

// ---------------- prep_w: Wa/Wb and Wproj into MFMA-fragment order ----------------
// wab  : [nt<4][kt<8][lane<64][j<8]  = bf16 W[(p=nt*16+(lane&15))][c=kt*32+8*(lane>>4)+j], p<32->Wa else Wb
// wfrag: [nt<8][kt<32][lane<64][j<8] = bf16 Wproj[z=nt*16+(lane&15)][korig], k'=kt*32+8*(lane>>4)+j,
//        c=k'&31, d=k'>>5, korig=c*32+d   (k' = d*32+c permutation; kt == d)
__global__ __launch_bounds__(256) void prep_w_kernel(
    const float* __restrict__ Wa, const float* __restrict__ Wb,
    const float* __restrict__ Wproj,
    unsigned short* __restrict__ wab, unsigned short* __restrict__ wfrag) {
  int gid = blockIdx.x * 256 + threadIdx.x;
  if (gid < 16384) {
    int e = gid;
    int j = e & 7, lane = (e >> 3) & 63, kt = (e >> 9) & 7, nt = e >> 12;
    int p = nt * 16 + (lane & 15);
    int c = kt * 32 + ((lane >> 4) << 3) + j;
    float v = (p < 32) ? Wa[p * 256 + c] : Wb[(p - 32) * 256 + c];
    wab[e] = f2bf(v);
  } else {
    int e = gid - 16384;
    int j = e & 7, lane = (e >> 3) & 63, kt = (e >> 9) & 31, nt = e >> 14;
    int z = nt * 16 + (lane & 15);
    int kp = kt * 32 + ((lane >> 4) << 3) + j;
    int c = kp & 31, d = kp >> 5;
    wfrag[e] = f2bf(Wproj[z * 1024 + c * 32 + d]);
  }
}

// ---------------- kernel_a: LN + MFMA projection + fragment-order transpose ----------------
// block = (i, s-half): 768 blocks, 256 threads (4 waves).
// outputs afrag/bfrag: [rowblock rb<768][kt<4][lane<64][j<8] bf16,
//   element = a_t[rb*16+(lane&15)][s = kt*32 + 8*(lane>>4) + j],  a_t[(i*32+c)][s] = a[s,i,c]
//   afrag rb = i*2 + (c>>4);  bfrag rb = j*2 + (d>>4)
#define XS 264   // x_lds row stride (halfwords)
#define OS 66    // o_lds row stride (floats)
__global__ __launch_bounds__(256) void kernel_a(
    const float* __restrict__ msa, const float* __restrict__ gamma, const float* __restrict__ beta,
    const unsigned short* __restrict__ wab,
    unsigned short* __restrict__ afrag, unsigned short* __restrict__ bfrag) {
  __shared__ unsigned short xs[64 * XS];   // normalized x, bf16 [64 local s][256 c]
  __shared__ float os[64 * OS];            // proj result fp32 [64 local s][64 p]
  const int i  = blockIdx.x >> 1;
  const int sh = blockIdx.x & 1;           // s-half: s in [sh*64, sh*64+64)
  const int tid = threadIdx.x;
  const int w = tid >> 6, lane = tid & 63;
  const int gq = lane >> 4, nlo = lane & 15;

  const float4 g4  = *(const float4*)(gamma + lane * 4);
  const float4 be4 = *(const float4*)(beta  + lane * 4);

  // phase 1: LayerNorm, one row per wave per iter
  for (int it = 0; it < 16; ++it) {
    const int sl = it * 4 + w;
    const int s  = sh * 64 + sl;
    const float4 v = *(const float4*)(msa + (size_t)(s * 384 + i) * 256 + lane * 4);
    float sum = v.x + v.y + v.z + v.w;
    float sq  = fmaf(v.x, v.x, fmaf(v.y, v.y, fmaf(v.z, v.z, v.w * v.w)));
#pragma unroll
    for (int off = 32; off >= 1; off >>= 1) {
      sum += __shfl_xor(sum, off);
      sq  += __shfl_xor(sq,  off);
    }
    const float mu   = sum * (1.f / 256.f);
    const float var  = sq * (1.f / 256.f) - mu * mu;
    const float rstd = rsqrtf(var + 1e-5f);
    unsigned int lo = (unsigned int)f2bf((v.x - mu) * rstd * g4.x + be4.x)
                    | ((unsigned int)f2bf((v.y - mu) * rstd * g4.y + be4.y) << 16);
    unsigned int hi = (unsigned int)f2bf((v.z - mu) * rstd * g4.z + be4.z)
                    | ((unsigned int)f2bf((v.w - mu) * rstd * g4.w + be4.w) << 16);
    *(uint2*)&xs[sl * XS + lane * 4] = make_uint2(lo, hi);
  }
  __syncthreads();

  // phase 2: MFMA projection  o[s][p] = sum_c x[s][c] * W[p][c]; wave w owns rows w*16..+16
  const f32x4 z4 = {0.f, 0.f, 0.f, 0.f};
  f32x4 acc[4];
#pragma unroll
  for (int nt = 0; nt < 4; ++nt) acc[nt] = z4;
  for (int kt = 0; kt < 8; ++kt) {
    const s8v av = *(const s8v*)&xs[(w * 16 + nlo) * XS + kt * 32 + gq * 8];
#pragma unroll
    for (int nt = 0; nt < 4; ++nt) {
      const s8v bv = ((const s8v*)wab)[(nt * 8 + kt) * 64 + lane];
      acc[nt] = __builtin_amdgcn_mfma_f32_16x16x32_bf16(av, bv, acc[nt], 0, 0, 0);
    }
  }
#pragma unroll
  for (int nt = 0; nt < 4; ++nt)
#pragma unroll
    for (int r = 0; r < 4; ++r)
      os[(w * 16 + gq * 4 + r) * OS + nt * 16 + nlo] = acc[nt][r];
  __syncthreads();

  // phase 3: fragment-order transposed write to afrag/bfrag
#pragma unroll
  for (int q = 0; q < 2; ++q) {
    const int set = q * 256 + tid;           // < 512
    const int lf  = set & 63;                // fragment lane
    const int ktl = (set >> 6) & 1;          // local k-tile (32 s each)
    const int hi2 = (set >> 7) & 1;          // c/d half (16)
    const int mat = (set >> 8) & 1;          // 0 = a, 1 = b
    const int g2  = lf >> 4;
    const int p   = mat * 32 + (lf & 15) + 16 * hi2;
    s8v pk;
#pragma unroll
    for (int j = 0; j < 8; ++j) {
      const int srow = ktl * 32 + g2 * 8 + j;
      pk[j] = (short)f2bf(os[srow * OS + p]);
    }
    unsigned short* dst = mat ? bfrag : afrag;
    const int rb = i * 2 + hi2;
    const int kt = sh * 2 + ktl;
    *(s8v*)(dst + ((size_t)((rb * 4 + kt) * 64 + lf)) * 8) = pk;
  }
}

// ---------------- kernel_main: persistent producer/consumer pipeline ----------------
// 256 blocks (1/CU), 512 thr = 4 producer waves + 4 consumer waves (1 P + 1 C per SIMD).
// Each block owns 9 tiles (8i x 8j = 64 ij) in its XCD region (12bi x 24bj per XCD).
// Per tile: 2 d-half chunks. Phase g: producers write stage-1 chunk g into t[g&1];
// consumers run stage-2 on chunk g-1 from t[(g-1)&1]. One barrier per phase.
// t layout: row = iloc*8 + jl (64 rows), hw = dl*32 + (c ^ 8*((dl>>1)&3)), stride TS4.
//   (conflict-free: b64 writes 4-pass min, b128 reads 8-pass min, verified by bank arith)
// stage-1 (producer wp): wave tile 64m x 128n, two n-half passes of acc[4][4].
// stage-2 (consumer wp): wave tile 64ij x 32z (z-block wp*32), acc2[4][2] persists over 2 chunks.
#define TS4 520
#define TBUF (64 * TS4)
__global__ __launch_bounds__(512, 2) void kernel_main(
    const unsigned short* __restrict__ afrag, const unsigned short* __restrict__ bfrag,
    const unsigned short* __restrict__ wfrag, const float* __restrict__ bproj,
    float* __restrict__ out) {
  extern __shared__ unsigned short t[];      // [2][64][TS4] = 133120 B
  const int b = blockIdx.x;                  // 256 blocks
  const int x = b & 7, l = b >> 3;           // XCD id, local id
  const int bi0 = (x >> 1) * 12, bj0 = (x & 1) * 24;
  const int tid = threadIdx.x;
  const int wave = tid >> 6, lane = tid & 63;
  const int gq = lane >> 4, nlo = lane & 15;
  const bool producer = wave < 4;
  const int wp = wave & 3;

  const s8v* ag = (const s8v*)afrag;
  const s8v* bg = (const s8v*)bfrag;
  const s8v* wg = (const s8v*)wfrag;
  const f32x4 z4 = {0.f, 0.f, 0.f, 0.f};

  f32x4 acc2[4][2];
#pragma unroll
  for (int mt = 0; mt < 4; ++mt) { acc2[mt][0] = z4; acc2[mt][1] = z4; }
  const float bz0 = bproj[(wp * 2 + 0) * 16 + nlo];
  const float bz1 = bproj[(wp * 2 + 1) * 16 + nlo];

  const int NPH = 18;                        // 9 tiles x 2 chunks
  for (int g = 0; g <= NPH; ++g) {
    if (producer && g < NPH) {
      const int it = g >> 1, dc = g & 1;
      const int idx = l + 32 * it;
      const int bi = bi0 + idx % 12, bj = bj0 + idx / 12;
      unsigned short* tb = t + (g & 1) * TBUF;
#pragma unroll 1
      for (int ph = 0; ph < 2; ++ph) {       // n-half passes keep acc at [4][4]
        f32x4 acc[4][4];
#pragma unroll
        for (int mt = 0; mt < 4; ++mt)
#pragma unroll
          for (int nt = 0; nt < 4; ++nt) acc[mt][nt] = z4;
#pragma unroll 2
        for (int kt = 0; kt < 4; ++kt) {
          s8v av[4];
#pragma unroll
          for (int mt = 0; mt < 4; ++mt)
            av[mt] = ag[((bi * 16 + wp * 4 + mt) * 4 + kt) * 64 + lane];
#pragma unroll
          for (int nt = 0; nt < 4; ++nt) {
            const int jl = ph * 4 + nt;
            const s8v bv = bg[(((bj * 8 + jl) * 2 + dc) * 4 + kt) * 64 + lane];
#pragma unroll
            for (int mt = 0; mt < 4; ++mt)
              acc[mt][nt] = __builtin_amdgcn_mfma_f32_16x16x32_bf16(av[mt], bv, acc[mt][nt], 0, 0, 0);
          }
        }
        // write to t: row = iloc*8 + jl; hw = dl*32 + (c ^ 8*((dl>>1)&3)), dl = nlo
#pragma unroll
        for (int mt = 0; mt < 4; ++mt) {
          const int row0 = (wp * 2 + (mt >> 1)) * 8 + ph * 4;
          const int hw = nlo * 32 + ((16 * (mt & 1) + 4 * gq) ^ (8 * ((nlo >> 1) & 3)));
#pragma unroll
          for (int nt = 0; nt < 4; ++nt) {
            const unsigned int lo = (unsigned int)f2bf(acc[mt][nt][0] * 0.0078125f)
                                  | ((unsigned int)f2bf(acc[mt][nt][1] * 0.0078125f) << 16);
            const unsigned int hi = (unsigned int)f2bf(acc[mt][nt][2] * 0.0078125f)
                                  | ((unsigned int)f2bf(acc[mt][nt][3] * 0.0078125f) << 16);
            *(uint2*)&tb[(row0 + nt) * TS4 + hw] = make_uint2(lo, hi);
          }
        }
      }
    }
    if (!producer && g >= 1) {
      const int c = g - 1, it = c >> 1, dc = c & 1;
      const int idx = l + 32 * it;
      const int bi = bi0 + idx % 12, bj = bj0 + idx / 12;
      const unsigned short* tb = t + (c & 1) * TBUF;
#pragma unroll 2
      for (int kt2 = 0; kt2 < 16; ++kt2) {
        const int hwb = kt2 * 32 + 8 * (gq ^ ((kt2 >> 1) & 3));
        s8v av2[4];
#pragma unroll
        for (int mt = 0; mt < 4; ++mt)
          av2[mt] = *(const s8v*)&tb[(mt * 16 + nlo) * TS4 + hwb];
        const s8v wv0 = wg[((wp * 2 + 0) * 32 + dc * 16 + kt2) * 64 + lane];
        const s8v wv1 = wg[((wp * 2 + 1) * 32 + dc * 16 + kt2) * 64 + lane];
#pragma unroll
        for (int mt = 0; mt < 4; ++mt) {
          acc2[mt][0] = __builtin_amdgcn_mfma_f32_16x16x32_bf16(av2[mt], wv0, acc2[mt][0], 0, 0, 0);
          acc2[mt][1] = __builtin_amdgcn_mfma_f32_16x16x32_bf16(av2[mt], wv1, acc2[mt][1], 0, 0, 0);
        }
      }
      if (dc == 1) {                         // tile finished: epilogue + reset
#pragma unroll
        for (int zt = 0; zt < 2; ++zt) {
          const int z = (wp * 2 + zt) * 16 + nlo;
          const float bz = zt ? bz1 : bz0;
#pragma unroll
          for (int mt = 0; mt < 4; ++mt) {
#pragma unroll
            for (int r = 0; r < 4; ++r) {
              const int ij = mt * 16 + gq * 4 + r;
              const int gi = bi * 8 + (ij >> 3), gj = bj * 8 + (ij & 7);
              out[(size_t)(gi * 384 + gj) * 128 + z] = acc2[mt][zt][r] + bz;
            }
            acc2[mt][zt] = z4;
          }
        }
      }
    }
    __syncthreads();
  }
}

extern "C" void kernel_launch(void* const* d_in, const int* in_sizes, int n_in,
                              void* d_out, int out_size, void* d_ws, size_t ws_size,
                              hipStream_t stream) {
  const float* msa   = (const float*)d_in[0];
  const float* gam   = (const float*)d_in[1];
  const float* bet   = (const float*)d_in[2];
  const float* Wa    = (const float*)d_in[3];
  const float* Wb    = (const float*)d_in[4];
  const float* Wproj = (const float*)d_in[5];
  const float* bpr   = (const float*)d_in[6];
  float* out = (float*)d_out;

  // workspace layout (bf16 elems): afrag 3MB, bfrag 3MB, wab 32KB, wfrag 256KB
  if (ws_size < 6586368) return;
  unsigned short* afrag = (unsigned short*)d_ws;
  unsigned short* bfrag = afrag + 1572864;
  unsigned short* wab   = bfrag + 1572864;
  unsigned short* wfr   = wab + 16384;

  (void)hipFuncSetAttribute(reinterpret_cast<const void*>(kernel_main),
                            hipFuncAttributeMaxDynamicSharedMemorySize, 2 * TBUF * 2);

  prep_w_kernel<<<576, 256, 0, stream>>>(Wa, Wb, Wproj, wab, wfr);
  kernel_a<<<768, 256, 0, stream>>>(msa, gam, bet, wab, afrag, bfrag);
  kernel_main<<<256, 512, 2 * TBUF * 2, stream>>>(afrag, bfrag, wfr, bpr, out);
}

// Round 5
// 149.196 us; speedup vs baseline: 1.9376x; 1.4297x over previous
//
#include <hip/hip_runtime.h>
#include <hip/hip_bf16.h>

typedef short s8v  __attribute__((ext_vector_type(8)));
typedef float f32x4 __attribute__((ext_vector_type(4)));

// RNE float -> bf16 bits
__device__ __forceinline__ unsigned short f2bf(float f) {
  unsigned int b = __float_as_uint(f);
  b += 0x7fffu + ((b >> 16) & 1u);
  return (unsigned short)(b >> 16);
}

// ---------------- prep_w: Wa/Wb and Wproj into MFMA-fragment order ----------------
// wab  : [nt<4][kt<8][lane<64][j<8]  = bf16 W[(p=nt*16+(lane&15))][c=kt*32+8*(lane>>4)+j], p<32->Wa else Wb
// wfrag: [nt<8][kt<32][lane<64][j<8] = bf16 Wproj[z=nt*16+(lane&15)][korig], k'=kt*32+8*(lane>>4)+j,
//        c=k'&31, d=k'>>5, korig=c*32+d   (k' = d*32+c permutation; kt == d)
__global__ __launch_bounds__(256) void prep_w_kernel(
    const float* __restrict__ Wa, const float* __restrict__ Wb,
    const float* __restrict__ Wproj,
    unsigned short* __restrict__ wab, unsigned short* __restrict__ wfrag) {
  int gid = blockIdx.x * 256 + threadIdx.x;
  if (gid < 16384) {
    int e = gid;
    int j = e & 7, lane = (e >> 3) & 63, kt = (e >> 9) & 7, nt = e >> 12;
    int p = nt * 16 + (lane & 15);
    int c = kt * 32 + ((lane >> 4) << 3) + j;
    float v = (p < 32) ? Wa[p * 256 + c] : Wb[(p - 32) * 256 + c];
    wab[e] = f2bf(v);
  } else {
    int e = gid - 16384;
    int j = e & 7, lane = (e >> 3) & 63, kt = (e >> 9) & 31, nt = e >> 14;
    int z = nt * 16 + (lane & 15);
    int kp = kt * 32 + ((lane >> 4) << 3) + j;
    int c = kp & 31, d = kp >> 5;
    wfrag[e] = f2bf(Wproj[z * 1024 + c * 32 + d]);
  }
}

// ---------------- kernel_a: LN + MFMA projection + fragment-order transpose ----------------
// block = (i, s-half): 768 blocks, 256 threads (4 waves).
// outputs afrag/bfrag: [rowblock rb<768][kt<4][lane<64][j<8] bf16,
//   element = a_t[rb*16+(lane&15)][s = kt*32 + 8*(lane>>4) + j],  a_t[(i*32+c)][s] = a[s,i,c]
//   afrag rb = i*2 + (c>>4);  bfrag rb = j*2 + (d>>4)
#define XS 264   // x_lds row stride (halfwords)
#define OS 66    // o_lds row stride (floats)
__global__ __launch_bounds__(256) void kernel_a(
    const float* __restrict__ msa, const float* __restrict__ gamma, const float* __restrict__ beta,
    const unsigned short* __restrict__ wab,
    unsigned short* __restrict__ afrag, unsigned short* __restrict__ bfrag) {
  __shared__ unsigned short xs[64 * XS];   // normalized x, bf16 [64 local s][256 c]
  __shared__ float os[64 * OS];            // proj result fp32 [64 local s][64 p]
  const int i  = blockIdx.x >> 1;
  const int sh = blockIdx.x & 1;           // s-half: s in [sh*64, sh*64+64)
  const int tid = threadIdx.x;
  const int w = tid >> 6, lane = tid & 63;
  const int gq = lane >> 4, nlo = lane & 15;

  const float4 g4  = *(const float4*)(gamma + lane * 4);
  const float4 be4 = *(const float4*)(beta  + lane * 4);

  // phase 1: LayerNorm, one row per wave per iter
  for (int it = 0; it < 16; ++it) {
    const int sl = it * 4 + w;
    const int s  = sh * 64 + sl;
    const float4 v = *(const float4*)(msa + (size_t)(s * 384 + i) * 256 + lane * 4);
    float sum = v.x + v.y + v.z + v.w;
    float sq  = fmaf(v.x, v.x, fmaf(v.y, v.y, fmaf(v.z, v.z, v.w * v.w)));
#pragma unroll
    for (int off = 32; off >= 1; off >>= 1) {
      sum += __shfl_xor(sum, off);
      sq  += __shfl_xor(sq,  off);
    }
    const float mu   = sum * (1.f / 256.f);
    const float var  = sq * (1.f / 256.f) - mu * mu;
    const float rstd = rsqrtf(var + 1e-5f);
    unsigned int lo = (unsigned int)f2bf((v.x - mu) * rstd * g4.x + be4.x)
                    | ((unsigned int)f2bf((v.y - mu) * rstd * g4.y + be4.y) << 16);
    unsigned int hi = (unsigned int)f2bf((v.z - mu) * rstd * g4.z + be4.z)
                    | ((unsigned int)f2bf((v.w - mu) * rstd * g4.w + be4.w) << 16);
    *(uint2*)&xs[sl * XS + lane * 4] = make_uint2(lo, hi);
  }
  __syncthreads();

  // phase 2: MFMA projection  o[s][p] = sum_c x[s][c] * W[p][c]; wave w owns rows w*16..+16
  const f32x4 z4 = {0.f, 0.f, 0.f, 0.f};
  f32x4 acc[4];
#pragma unroll
  for (int nt = 0; nt < 4; ++nt) acc[nt] = z4;
  for (int kt = 0; kt < 8; ++kt) {
    const s8v av = *(const s8v*)&xs[(w * 16 + nlo) * XS + kt * 32 + gq * 8];
#pragma unroll
    for (int nt = 0; nt < 4; ++nt) {
      const s8v bv = ((const s8v*)wab)[(nt * 8 + kt) * 64 + lane];
      acc[nt] = __builtin_amdgcn_mfma_f32_16x16x32_bf16(av, bv, acc[nt], 0, 0, 0);
    }
  }
#pragma unroll
  for (int nt = 0; nt < 4; ++nt)
#pragma unroll
    for (int r = 0; r < 4; ++r)
      os[(w * 16 + gq * 4 + r) * OS + nt * 16 + nlo] = acc[nt][r];
  __syncthreads();

  // phase 3: fragment-order transposed write to afrag/bfrag
#pragma unroll
  for (int q = 0; q < 2; ++q) {
    const int set = q * 256 + tid;           // < 512
    const int lf  = set & 63;                // fragment lane
    const int ktl = (set >> 6) & 1;          // local k-tile (32 s each)
    const int hi2 = (set >> 7) & 1;          // c/d half (16)
    const int mat = (set >> 8) & 1;          // 0 = a, 1 = b
    const int g2  = lf >> 4;
    const int p   = mat * 32 + (lf & 15) + 16 * hi2;
    s8v pk;
#pragma unroll
    for (int j = 0; j < 8; ++j) {
      const int srow = ktl * 32 + g2 * 8 + j;
      pk[j] = (short)f2bf(os[srow * OS + p]);
    }
    unsigned short* dst = mat ? bfrag : afrag;
    const int rb = i * 2 + hi2;
    const int kt = sh * 2 + ktl;
    *(s8v*)(dst + ((size_t)((rb * 4 + kt) * 64 + lf)) * 8) = pk;
  }
}

// ---------------- kernel_main: fused, d-half chunked, 2 blocks/CU, homogeneous waves ----------------
// block = 8i x 8j tile (64 ij); 8 waves; 66.56 KB LDS; <=128 VGPR -> 2 blocks/CU (16 waves/CU).
// dc loop (d-half chunk, k''-range 512):
//   stage1: outer[m=(i,c)<256][n=(jloc,dl)<128] = sum_s a b, K=128.
//           wave grid 4m x 2n, TWO n-half passes, per-pass wave tile 64m x 32n (acc[4][2]=32 regs).
//   t[row=iloc*8+jloc <64][p = dl*32 + (c ^ 8*((dl>>1)&3))] bf16 *1/128, stride TS5.
//   stage2: acc2[4] += t x wfrag-chunk: wave = 16 z (z-exclusive), 64 ij rows, K=512 (kt2<16).
// Swizzle consistency: read base kt2*32 + 8*(gq ^ ((kt2>>1)&3)) recovers natural k order (verified algebra).
#define TS5 520
__global__ __launch_bounds__(512, 4) void kernel_main(
    const unsigned short* __restrict__ afrag, const unsigned short* __restrict__ bfrag,
    const unsigned short* __restrict__ wfrag, const float* __restrict__ bproj,
    float* __restrict__ out) {
  extern __shared__ unsigned short t[];      // [64][TS5]
  // bijective XCD swizzle: 2304 % 8 == 0 -> contiguous chunk of 288 per XCD
  const int bid = (blockIdx.x & 7) * 288 + (blockIdx.x >> 3);
  const int bi = bid / 48, bj = bid % 48;
  const int tid = threadIdx.x;
  const int wave = tid >> 6, lane = tid & 63;
  const int wm = wave >> 1, wn = wave & 1;   // stage1 wave grid 4m x 2n
  const int gq = lane >> 4, nlo = lane & 15;

  const s8v* ag = (const s8v*)afrag;
  const s8v* bg = (const s8v*)bfrag;
  const s8v* wg = (const s8v*)wfrag;
  const f32x4 z4 = {0.f, 0.f, 0.f, 0.f};

  f32x4 acc2[4];                             // persistent over both chunks (16 VGPR)
#pragma unroll
  for (int mt = 0; mt < 4; ++mt) acc2[mt] = z4;

#pragma unroll 1
  for (int dc = 0; dc < 2; ++dc) {
    // ---- stage 1: two n-half passes ----
#pragma unroll 1
    for (int ph = 0; ph < 2; ++ph) {
      f32x4 acc[4][2];
#pragma unroll
      for (int mt = 0; mt < 4; ++mt) { acc[mt][0] = z4; acc[mt][1] = z4; }
#pragma unroll 2
      for (int kt = 0; kt < 4; ++kt) {
        s8v av[4];
#pragma unroll
        for (int mt = 0; mt < 4; ++mt)
          av[mt] = ag[((bi * 16 + wm * 4 + mt) * 4 + kt) * 64 + lane];
        s8v bv[2];
#pragma unroll
        for (int nt = 0; nt < 2; ++nt)
          bv[nt] = bg[(((bj * 8 + ph * 4 + wn * 2 + nt) * 2 + dc) * 4 + kt) * 64 + lane];
#pragma unroll
        for (int mt = 0; mt < 4; ++mt)
#pragma unroll
          for (int nt = 0; nt < 2; ++nt)
            acc[mt][nt] = __builtin_amdgcn_mfma_f32_16x16x32_bf16(av[mt], bv[nt], acc[mt][nt], 0, 0, 0);
      }
      // protect t from overwrite: chunk-0 readers must be done (only needed once, before first write of dc=1)
      if (dc && ph == 0) __syncthreads();
      // write: row = iloc*8 + jloc; hw = dl*32 + (c0 ^ 8*((dl>>1)&3)), dl = nlo
#pragma unroll
      for (int mt = 0; mt < 4; ++mt) {
        const int row0 = (wm * 2 + (mt >> 1)) * 8 + ph * 4 + wn * 2;
        const int c0 = (mt & 1) * 16 + 4 * gq;
        const int hw = nlo * 32 + (c0 ^ (8 * ((nlo >> 1) & 3)));
#pragma unroll
        for (int nt = 0; nt < 2; ++nt) {
          const unsigned int lo = (unsigned int)f2bf(acc[mt][nt][0] * 0.0078125f)
                                | ((unsigned int)f2bf(acc[mt][nt][1] * 0.0078125f) << 16);
          const unsigned int hi = (unsigned int)f2bf(acc[mt][nt][2] * 0.0078125f)
                                | ((unsigned int)f2bf(acc[mt][nt][3] * 0.0078125f) << 16);
          *(uint2*)&t[(row0 + nt) * TS5 + hw] = make_uint2(lo, hi);
        }
      }
    }
    __syncthreads();

    // ---- stage 2: wave owns z-block = wave*16..+16, all 64 ij rows, K-chunk 512 ----
#pragma unroll 2
    for (int kt2 = 0; kt2 < 16; ++kt2) {
      const int hwb = kt2 * 32 + 8 * (gq ^ ((kt2 >> 1) & 3));
      const s8v wv = wg[(wave * 32 + dc * 16 + kt2) * 64 + lane];
      s8v av2[4];
#pragma unroll
      for (int mt = 0; mt < 4; ++mt)
        av2[mt] = *(const s8v*)&t[(mt * 16 + nlo) * TS5 + hwb];
#pragma unroll
      for (int mt = 0; mt < 4; ++mt)
        acc2[mt] = __builtin_amdgcn_mfma_f32_16x16x32_bf16(av2[mt], wv, acc2[mt], 0, 0, 0);
    }
    if (!dc) __syncthreads();   // chunk-0 reads done before chunk-1 writes (paired with pre-write barrier)
  }

  // ---- epilogue ----
  const int z = wave * 16 + nlo;
  const float bz = bproj[z];
#pragma unroll
  for (int mt = 0; mt < 4; ++mt)
#pragma unroll
    for (int r = 0; r < 4; ++r) {
      const int ij = mt * 16 + gq * 4 + r;
      const int gi = bi * 8 + (ij >> 3), gj = bj * 8 + (ij & 7);
      out[(size_t)(gi * 384 + gj) * 128 + z] = acc2[mt][r] + bz;
    }
}

extern "C" void kernel_launch(void* const* d_in, const int* in_sizes, int n_in,
                              void* d_out, int out_size, void* d_ws, size_t ws_size,
                              hipStream_t stream) {
  const float* msa   = (const float*)d_in[0];
  const float* gam   = (const float*)d_in[1];
  const float* bet   = (const float*)d_in[2];
  const float* Wa    = (const float*)d_in[3];
  const float* Wb    = (const float*)d_in[4];
  const float* Wproj = (const float*)d_in[5];
  const float* bpr   = (const float*)d_in[6];
  float* out = (float*)d_out;

  // workspace layout (bf16 elems): afrag 3MB, bfrag 3MB, wab 32KB, wfrag 256KB
  if (ws_size < 6586368) return;
  unsigned short* afrag = (unsigned short*)d_ws;
  unsigned short* bfrag = afrag + 1572864;
  unsigned short* wab   = bfrag + 1572864;
  unsigned short* wfr   = wab + 16384;

  (void)hipFuncSetAttribute(reinterpret_cast<const void*>(kernel_main),
                            hipFuncAttributeMaxDynamicSharedMemorySize, 64 * TS5 * 2);

  prep_w_kernel<<<576, 256, 0, stream>>>(Wa, Wb, Wproj, wab, wfr);
  kernel_a<<<768, 256, 0, stream>>>(msa, gam, bet, wab, afrag, bfrag);
  kernel_main<<<2304, 512, 64 * TS5 * 2, stream>>>(afrag, bfrag, wfr, bpr, out);
}

// Round 6
// 134.700 us; speedup vs baseline: 2.1461x; 1.1076x over previous
//
#include <hip/hip_runtime.h>
#include <hip/hip_bf16.h>

typedef short s8v   __attribute__((ext_vector_type(8)));
typedef float f32x4 __attribute__((ext_vector_type(4)));
typedef float f32x16 __attribute__((ext_vector_type(16)));

// RNE float -> bf16 bits
__device__ __forceinline__ unsigned short f2bf(float f) {
  unsigned int b = __float_as_uint(f);
  b += 0x7fffu + ((b >> 16) & 1u);
  return (unsigned short)(b >> 16);
}

// ---------------- prep_w ----------------
// wab  : [nt<4][kt<8][lane<64][j<8] = bf16 W[p=nt*16+(lane&15)][c=kt*32+8*(lane>>4)+j]  (16x16x32 frag, kernel_a)
// wfrag: [zt<4][kt2<64][lane<64][j<8] = bf16 Wproj[z=zt*32+(lane&31)][korig],
//        k'' = kt2*16 + 8*(lane>>5) + j;  d = k''>>5, c = k''&31, korig = c*32 + d   (32x32x16 B frag)
__global__ __launch_bounds__(256) void prep_w_kernel(
    const float* __restrict__ Wa, const float* __restrict__ Wb,
    const float* __restrict__ Wproj,
    unsigned short* __restrict__ wab, unsigned short* __restrict__ wfrag) {
  int gid = blockIdx.x * 256 + threadIdx.x;
  if (gid < 16384) {
    int e = gid;
    int j = e & 7, lane = (e >> 3) & 63, kt = (e >> 9) & 7, nt = e >> 12;
    int p = nt * 16 + (lane & 15);
    int c = kt * 32 + ((lane >> 4) << 3) + j;
    float v = (p < 32) ? Wa[p * 256 + c] : Wb[(p - 32) * 256 + c];
    wab[e] = f2bf(v);
  } else {
    int e = gid - 16384;                     // < 131072
    int j = e & 7, lane = (e >> 3) & 63, kt2 = (e >> 9) & 63, zt = e >> 15;
    int z = zt * 32 + (lane & 31);
    int kpp = kt2 * 16 + ((lane >> 5) << 3) + j;
    int d = kpp >> 5, c = kpp & 31;
    wfrag[e] = f2bf(Wproj[z * 1024 + c * 32 + d]);
  }
}

// ---------------- kernel_a: LN + MFMA projection + 32x32-fragment transpose ----------------
// block = (i, s-half): 768 blocks, 256 threads (4 waves).
// afrag: [i<384][kt<8][lane<64][j<8] = bf16 a_t[i*32 + (lane&31)][s = kt*16 + 8*(lane>>5) + j]
// bfrag: [j<384][kt<8][lane<64][j8]  = bf16 b_t[j*32 + (lane&31)][s]      (identical layout)
#define XS 264   // x_lds row stride (halfwords)
#define OS 66    // o_lds row stride (floats)
__global__ __launch_bounds__(256) void kernel_a(
    const float* __restrict__ msa, const float* __restrict__ gamma, const float* __restrict__ beta,
    const unsigned short* __restrict__ wab,
    unsigned short* __restrict__ afrag, unsigned short* __restrict__ bfrag) {
  __shared__ unsigned short xs[64 * XS];   // normalized x, bf16 [64 local s][256 c]
  __shared__ float os[64 * OS];            // proj result fp32 [64 local s][64 p]
  const int i  = blockIdx.x >> 1;
  const int sh = blockIdx.x & 1;           // s-half: s in [sh*64, sh*64+64)
  const int tid = threadIdx.x;
  const int w = tid >> 6, lane = tid & 63;
  const int gq = lane >> 4, nlo = lane & 15;

  const float4 g4  = *(const float4*)(gamma + lane * 4);
  const float4 be4 = *(const float4*)(beta  + lane * 4);

  // phase 1: LayerNorm, one row per wave per iter
  for (int it = 0; it < 16; ++it) {
    const int sl = it * 4 + w;
    const int s  = sh * 64 + sl;
    const float4 v = *(const float4*)(msa + (size_t)(s * 384 + i) * 256 + lane * 4);
    float sum = v.x + v.y + v.z + v.w;
    float sq  = fmaf(v.x, v.x, fmaf(v.y, v.y, fmaf(v.z, v.z, v.w * v.w)));
#pragma unroll
    for (int off = 32; off >= 1; off >>= 1) {
      sum += __shfl_xor(sum, off);
      sq  += __shfl_xor(sq,  off);
    }
    const float mu   = sum * (1.f / 256.f);
    const float var  = sq * (1.f / 256.f) - mu * mu;
    const float rstd = rsqrtf(var + 1e-5f);
    unsigned int lo = (unsigned int)f2bf((v.x - mu) * rstd * g4.x + be4.x)
                    | ((unsigned int)f2bf((v.y - mu) * rstd * g4.y + be4.y) << 16);
    unsigned int hi = (unsigned int)f2bf((v.z - mu) * rstd * g4.z + be4.z)
                    | ((unsigned int)f2bf((v.w - mu) * rstd * g4.w + be4.w) << 16);
    *(uint2*)&xs[sl * XS + lane * 4] = make_uint2(lo, hi);
  }
  __syncthreads();

  // phase 2: MFMA projection  o[s][p] = sum_c x[s][c] * W[p][c]; wave w owns rows w*16..+16
  const f32x4 z4 = {0.f, 0.f, 0.f, 0.f};
  f32x4 acc[4];
#pragma unroll
  for (int nt = 0; nt < 4; ++nt) acc[nt] = z4;
  for (int kt = 0; kt < 8; ++kt) {
    const s8v av = *(const s8v*)&xs[(w * 16 + nlo) * XS + kt * 32 + gq * 8];
#pragma unroll
    for (int nt = 0; nt < 4; ++nt) {
      const s8v bv = ((const s8v*)wab)[(nt * 8 + kt) * 64 + lane];
      acc[nt] = __builtin_amdgcn_mfma_f32_16x16x32_bf16(av, bv, acc[nt], 0, 0, 0);
    }
  }
#pragma unroll
  for (int nt = 0; nt < 4; ++nt)
#pragma unroll
    for (int r = 0; r < 4; ++r)
      os[(w * 16 + gq * 4 + r) * OS + nt * 16 + nlo] = acc[nt][r];
  __syncthreads();

  // phase 3: 32x32-fragment-order transposed write to afrag/bfrag
#pragma unroll
  for (int q = 0; q < 2; ++q) {
    const int set = q * 256 + tid;           // < 512
    const int lf  = set & 63;                // fragment lane
    const int ktl = (set >> 6) & 3;          // local k-tile (16 s each)
    const int mat = set >> 8;                // 0 = a, 1 = b
    const int gg  = lf >> 5;
    const int p   = mat * 32 + (lf & 31);
    s8v pk;
#pragma unroll
    for (int j = 0; j < 8; ++j)
      pk[j] = (short)f2bf(os[(ktl * 16 + 8 * gg + j) * OS + p]);
    unsigned short* dst = mat ? bfrag : afrag;
    *(s8v*)(dst + ((size_t)((i * 8 + sh * 4 + ktl) * 64 + lf)) * 8) = pk;
  }
}

// ---------------- kernel_main: fused outer-product + projection, 32x32 MFMA, 16 waves ----------------
// block = 8i x 8j (64 ij); 1024 threads (16 waves); 129 KB LDS -> 1 block/CU, 4 waves/SIMD.
// stage1: outer[m=(i,c)<256][n=(j,d)<256] = sum_s a b, K=128. wave grid 4m x 4n, wave tile 64x64,
//         acc = 4 x f32x16 (64 VGPR). t[row=iloc*8+jloc][k''] bf16 *1/128, k'' = d*32 + (c ^ 8*(d&3)), stride TSM.
// stage2: out[ij][z] = t x wfrag, M=64(2 m-tiles), N=128(4 z-tiles), K=1024(64 ksteps of 16).
//         waves = (zt<4, kh<4); wave covers both m-tiles, z-tile zt, k-quarter kh -> every LDS read
//         feeds 2 MFMAs, every wv read once. k-quarter partials reduced via LDS scratch (reuses t).
#define TSM 1032
__global__ __launch_bounds__(1024, 4) void kernel_main(
    const unsigned short* __restrict__ afrag, const unsigned short* __restrict__ bfrag,
    const unsigned short* __restrict__ wfrag, const float* __restrict__ bproj,
    float* __restrict__ out) {
  extern __shared__ unsigned short t[];      // [64][TSM] bf16; later reused as f32 scratch
  const int bid = blockIdx.x;                // no XCD swizzle (R1 evidence: lowest FETCH)
  const int bi = bid / 48, bj = bid % 48;
  const int tid = threadIdx.x;
  const int wave = tid >> 6, lane = tid & 63;
  const int g = lane >> 5, l31 = lane & 31;

  const s8v* ag = (const s8v*)afrag;
  const s8v* bg = (const s8v*)bfrag;
  const s8v* wg = (const s8v*)wfrag;

  // ---- stage 1 ----
  {
    const int wm = wave >> 2, wn = wave & 3;
    f32x16 a00 = {}, a01 = {}, a10 = {}, a11 = {};
#pragma unroll 2
    for (int kt = 0; kt < 8; ++kt) {
      const s8v av0 = ag[((bi * 8 + wm * 2 + 0) * 8 + kt) * 64 + lane];
      const s8v av1 = ag[((bi * 8 + wm * 2 + 1) * 8 + kt) * 64 + lane];
      const s8v bv0 = bg[((bj * 8 + wn * 2 + 0) * 8 + kt) * 64 + lane];
      const s8v bv1 = bg[((bj * 8 + wn * 2 + 1) * 8 + kt) * 64 + lane];
      a00 = __builtin_amdgcn_mfma_f32_32x32x16_bf16(av0, bv0, a00, 0, 0, 0);
      a01 = __builtin_amdgcn_mfma_f32_32x32x16_bf16(av0, bv1, a01, 0, 0, 0);
      a10 = __builtin_amdgcn_mfma_f32_32x32x16_bf16(av1, bv0, a10, 0, 0, 0);
      a11 = __builtin_amdgcn_mfma_f32_32x32x16_bf16(av1, bv1, a11, 0, 0, 0);
    }
    // store: D col = lane&31 = d; D row c = (r&3)+8*(r>>2)+4g; hw = d*32 + (c ^ 8*(d&3))
    const int xr = 8 * (l31 & 3);
#pragma unroll
    for (int mt = 0; mt < 2; ++mt)
#pragma unroll
      for (int nt = 0; nt < 2; ++nt) {
        const f32x16& a = (mt == 0) ? (nt == 0 ? a00 : a01) : (nt == 0 ? a10 : a11);
        const int row_t = (wm * 2 + mt) * 8 + wn * 2 + nt;
#pragma unroll
        for (int q = 0; q < 4; ++q) {
          const int c0 = q * 8 + 4 * g;
          const int hw = l31 * 32 + (c0 ^ xr);
          const unsigned int lo = (unsigned int)f2bf(a[q * 4 + 0] * 0.0078125f)
                                | ((unsigned int)f2bf(a[q * 4 + 1] * 0.0078125f) << 16);
          const unsigned int hi = (unsigned int)f2bf(a[q * 4 + 2] * 0.0078125f)
                                | ((unsigned int)f2bf(a[q * 4 + 3] * 0.0078125f) << 16);
          *(uint2*)&t[row_t * TSM + hw] = make_uint2(lo, hi);
        }
      }
  }
  __syncthreads();

  // ---- stage 2 ----
  const int zt = wave & 3, kh = wave >> 2;
  f32x16 p0 = {}, p1 = {};
#pragma unroll 4
  for (int k2 = 0; k2 < 16; ++k2) {
    const int kt2 = kh * 16 + k2;
    const int d = kt2 >> 1;
    const int hwb = d * 32 + ((((kt2 & 1) * 16) + 8 * g) ^ (8 * (d & 3)));
    const s8v wv = wg[((zt * 64 + kt2) * 64 + lane)];
    const s8v a0 = *(const s8v*)&t[l31 * TSM + hwb];
    const s8v a1 = *(const s8v*)&t[(32 + l31) * TSM + hwb];
    p0 = __builtin_amdgcn_mfma_f32_32x32x16_bf16(a0, wv, p0, 0, 0, 0);
    p1 = __builtin_amdgcn_mfma_f32_32x32x16_bf16(a1, wv, p1, 0, 0, 0);
  }
  __syncthreads();

  // ---- k-quarter reduction via LDS scratch (reuses t; 12 slots x 8 KB = 96 KB) ----
  float* sc = (float*)t;
  if (kh > 0) {
    const int slot = zt * 3 + (kh - 1);
#pragma unroll
    for (int r = 0; r < 16; ++r) {
      sc[((slot * 2 + 0) * 16 + r) * 64 + lane] = p0[r];
      sc[((slot * 2 + 1) * 16 + r) * 64 + lane] = p1[r];
    }
  }
  __syncthreads();
  if (kh == 0) {
#pragma unroll
    for (int s2 = 0; s2 < 3; ++s2) {
      const int slot = zt * 3 + s2;
#pragma unroll
      for (int r = 0; r < 16; ++r) {
        p0[r] += sc[((slot * 2 + 0) * 16 + r) * 64 + lane];
        p1[r] += sc[((slot * 2 + 1) * 16 + r) * 64 + lane];
      }
    }
    const int z = zt * 32 + l31;
    const float bz = bproj[z];
#pragma unroll
    for (int r = 0; r < 16; ++r) {
      {
        const int ij = (r & 3) + 8 * (r >> 2) + 4 * g;
        const int gi = bi * 8 + (ij >> 3), gj = bj * 8 + (ij & 7);
        out[(size_t)(gi * 384 + gj) * 128 + z] = p0[r] + bz;
      }
      {
        const int ij = 32 + (r & 3) + 8 * (r >> 2) + 4 * g;
        const int gi = bi * 8 + (ij >> 3), gj = bj * 8 + (ij & 7);
        out[(size_t)(gi * 384 + gj) * 128 + z] = p1[r] + bz;
      }
    }
  }
}

extern "C" void kernel_launch(void* const* d_in, const int* in_sizes, int n_in,
                              void* d_out, int out_size, void* d_ws, size_t ws_size,
                              hipStream_t stream) {
  const float* msa   = (const float*)d_in[0];
  const float* gam   = (const float*)d_in[1];
  const float* bet   = (const float*)d_in[2];
  const float* Wa    = (const float*)d_in[3];
  const float* Wb    = (const float*)d_in[4];
  const float* Wproj = (const float*)d_in[5];
  const float* bpr   = (const float*)d_in[6];
  float* out = (float*)d_out;

  // workspace layout (bf16 elems): afrag 3MB, bfrag 3MB, wab 32KB, wfrag 256KB
  if (ws_size < 6586368) return;
  unsigned short* afrag = (unsigned short*)d_ws;
  unsigned short* bfrag = afrag + 1572864;
  unsigned short* wab   = bfrag + 1572864;
  unsigned short* wfr   = wab + 16384;

  (void)hipFuncSetAttribute(reinterpret_cast<const void*>(kernel_main),
                            hipFuncAttributeMaxDynamicSharedMemorySize, 64 * TSM * 2);

  prep_w_kernel<<<576, 256, 0, stream>>>(Wa, Wb, Wproj, wab, wfr);
  kernel_a<<<768, 256, 0, stream>>>(msa, gam, bet, wab, afrag, bfrag);
  kernel_main<<<2304, 1024, 64 * TSM * 2, stream>>>(afrag, bfrag, wfr, bpr, out);
}